// Round 1
// baseline (330.347 us; speedup 1.0000x reference)
//
#include <hip/hip_runtime.h>
#include <stdint.h>

typedef unsigned short u16;
typedef __bf16 bf16x8 __attribute__((ext_vector_type(8)));
typedef float f32x4 __attribute__((ext_vector_type(4)));

#define BM 128
#define BN 128
#define BK 32

// fp32 -> bf16 round-to-nearest-even, bit-level (avoids hip_bf16.h API drift)
__device__ __forceinline__ u16 f2bf(float f) {
    union { float f; unsigned int u; } a; a.f = f;
    unsigned int u = a.u;
    u += 0x7FFFu + ((u >> 16) & 1u);
    return (u16)(u >> 16);
}

__device__ __forceinline__ void async_load16(const void* g, void* l) {
    __builtin_amdgcn_global_load_lds(
        (const __attribute__((address_space(1))) void*)g,
        (__attribute__((address_space(3))) void*)l,
        16, 0, 0);
}

// ---------------------------------------------------------------------------
// C[M,N] = A[M,K] * Bt[N,K]^T  (bf16 in, fp32 acc). m97-style structure:
// 128x128 tile, BK=32, 4 waves in 2x2, each wave 64x64 = 4x4 MFMA subtiles.
// OUT_BF16: store bf16; CSKIP: skip blocks strictly above diagonal (S=QK^T);
// CKLIM: limit K-loop to causal extent (O=P*V^T, P upper-tri is zero).
// ---------------------------------------------------------------------------
template<bool OUT_BF16, bool CSKIP, bool CKLIM>
__global__ __launch_bounds__(256)
void gemm_bt(const u16* __restrict__ A, long long sAb,
             const u16* __restrict__ Bt, long long sBb,
             void* __restrict__ Cv, long long sCb,
             int M, int N, int K, float scale)
{
    const int bn = blockIdx.x, bm = blockIdx.y, bz = blockIdx.z;
    if (CSKIP && bn * BN > bm * BM + (BM - 1)) return;  // fully-masked tile
    A  += (size_t)bz * sAb;
    Bt += (size_t)bz * sBb;

    const int tid  = threadIdx.x;
    const int lane = tid & 63;
    const int wv   = tid >> 6;        // wave 0..3
    const int wm   = wv >> 1;         // wave row (0..1)
    const int wn   = wv & 1;          // wave col (0..1)

    __shared__ __attribute__((aligned(16))) u16 As[BM * BK];
    __shared__ __attribute__((aligned(16))) u16 Bs[BN * BK];

    f32x4 acc[4][4] = {};

    const int rowA0 = bm * BM, rowB0 = bn * BN;
    // global_load_lds staging: wave wv covers chunks {2*wv, 2*wv+1}; each chunk
    // = 1KB = 64 lanes x 16B. Flat LDS elem (chunk*512 + lane*8) -> row-major
    // [128][32]: row = chunk*16 + lane/4, col = (lane&3)*8.
    const int srow = lane >> 2;
    const int scol = (lane & 3) * 8;

    int kEnd = K;
    if (CKLIM) { int ke = (bm + 1) * BM; kEnd = ke < K ? ke : K; }

    const int lm   = lane & 15;       // MFMA m/n index
    const int quad = lane >> 4;       // MFMA k-group
    const int lk   = quad * 8;

    for (int k0 = 0; k0 < kEnd; k0 += BK) {
        #pragma unroll
        for (int c = 0; c < 2; ++c) {
            const int cc = wv * 2 + c;
            const int r  = cc * 16 + srow;
            async_load16(&A [(size_t)(rowA0 + r) * K + k0 + scol], &As[cc * 512 + lane * 8]);
            async_load16(&Bt[(size_t)(rowB0 + r) * K + k0 + scol], &Bs[cc * 512 + lane * 8]);
        }
        __syncthreads();   // compiler emits vmcnt(0) drain before barrier

        bf16x8 af[4], bfr[4];
        #pragma unroll
        for (int i = 0; i < 4; ++i)
            af[i] = *reinterpret_cast<const bf16x8*>(&As[(wm * 64 + i * 16 + lm) * BK + lk]);
        #pragma unroll
        for (int j = 0; j < 4; ++j)
            bfr[j] = *reinterpret_cast<const bf16x8*>(&Bs[(wn * 64 + j * 16 + lm) * BK + lk]);
        #pragma unroll
        for (int i = 0; i < 4; ++i)
            #pragma unroll
            for (int j = 0; j < 4; ++j)
                acc[i][j] = __builtin_amdgcn_mfma_f32_16x16x32_bf16(af[i], bfr[j], acc[i][j], 0, 0, 0);
        __syncthreads();   // all reads done before next stage overwrites
    }

    // Epilogue. C/D layout (m89-verified): col = lane&15, row = quad*4 + reg.
    if (OUT_BF16) {
        u16* C = (u16*)Cv + (size_t)bz * sCb;
        #pragma unroll
        for (int i = 0; i < 4; ++i)
            #pragma unroll
            for (int j = 0; j < 4; ++j) {
                const int r0 = rowA0 + wm * 64 + i * 16 + quad * 4;
                const int c0 = rowB0 + wn * 64 + j * 16 + lm;
                #pragma unroll
                for (int g = 0; g < 4; ++g)
                    C[(size_t)(r0 + g) * N + c0] = f2bf(acc[i][j][g] * scale);
            }
    } else {
        float* C = (float*)Cv + (size_t)bz * sCb;
        #pragma unroll
        for (int i = 0; i < 4; ++i)
            #pragma unroll
            for (int j = 0; j < 4; ++j) {
                const int r0 = rowA0 + wm * 64 + i * 16 + quad * 4;
                const int c0 = rowB0 + wn * 64 + j * 16 + lm;
                #pragma unroll
                for (int g = 0; g < 4; ++g)
                    C[(size_t)(r0 + g) * N + c0] = acc[i][j][g] * scale;
            }
    }
}

// x fp32 -> bf16, 8 elems/thread
__global__ __launch_bounds__(256)
void cast_x(const float* __restrict__ x, u16* __restrict__ o, long long n)
{
    long long i = ((long long)blockIdx.x * blockDim.x + threadIdx.x) * 8;
    if (i >= n) return;
    const float4 a = *(const float4*)(x + i);
    const float4 b = *(const float4*)(x + i + 4);
    union { u16 u[8]; float4 v; } r;
    r.u[0] = f2bf(a.x); r.u[1] = f2bf(a.y); r.u[2] = f2bf(a.z); r.u[3] = f2bf(a.w);
    r.u[4] = f2bf(b.x); r.u[5] = f2bf(b.y); r.u[6] = f2bf(b.z); r.u[7] = f2bf(b.w);
    *(float4*)(o + i) = r.v;
}

// W[rows][cols] fp32 -> Wt[cols][rows] bf16 (LDS tile transpose, +1 pad)
__global__ __launch_bounds__(256)
void castT_w(const float* __restrict__ W, u16* __restrict__ Wt, int rows, int cols)
{
    __shared__ u16 t[32][33];
    const int c0 = blockIdx.x * 32, r0 = blockIdx.y * 32;
    const int tx = threadIdx.x & 31, ty = threadIdx.x >> 5;  // ty 0..7
    #pragma unroll
    for (int s = 0; s < 32; s += 8)
        t[ty + s][tx] = f2bf(W[(size_t)(r0 + ty + s) * cols + c0 + tx]);
    __syncthreads();
    #pragma unroll
    for (int s = 0; s < 32; s += 8)
        Wt[(size_t)(c0 + ty + s) * rows + r0 + tx] = t[tx][ty + s];
}

// V[rows][cols] bf16 -> Vt[cols][rows] bf16, batched via blockIdx.z
__global__ __launch_bounds__(256)
void transpose_b(const u16* __restrict__ V, long long sVb,
                 u16* __restrict__ Vt, long long sVtb, int rows, int cols)
{
    V  += (size_t)blockIdx.z * sVb;
    Vt += (size_t)blockIdx.z * sVtb;
    __shared__ u16 t[32][33];
    const int c0 = blockIdx.x * 32, r0 = blockIdx.y * 32;
    const int tx = threadIdx.x & 31, ty = threadIdx.x >> 5;
    #pragma unroll
    for (int s = 0; s < 32; s += 8)
        t[ty + s][tx] = V[(size_t)(r0 + ty + s) * cols + c0 + tx];
    __syncthreads();
    #pragma unroll
    for (int s = 0; s < 32; s += 8)
        Vt[(size_t)(c0 + ty + s) * rows + r0 + tx] = t[tx][ty + s];
}

// Causal row softmax: P[i][j] = softmax_j<=i(S[i][:]*scale), P[i][j>i] = 0 (bf16)
// One 256-thread block per row; T must be 2048 (8 elems/thread).
__global__ __launch_bounds__(256)
void softmax_causal(const float* __restrict__ S, long long sSb,
                    u16* __restrict__ P, long long sPb, int T, float kfac)
{
    const int row = blockIdx.x, bz = blockIdx.y;
    const float* Sr = S + (size_t)bz * sSb + (size_t)row * T;
    u16*         Pr = P + (size_t)bz * sPb + (size_t)row * T;
    const int tid = threadIdx.x, lane = tid & 63, wv = tid >> 6;

    float v[8];
    float mx = -1e30f;
    #pragma unroll
    for (int u = 0; u < 8; ++u) {
        const int j = tid + u * 256;
        v[u] = (j <= row) ? Sr[j] : -1e30f;
        mx = fmaxf(mx, v[u]);
    }
    #pragma unroll
    for (int o = 32; o; o >>= 1) mx = fmaxf(mx, __shfl_xor(mx, o));
    __shared__ float redm[4];
    if (lane == 0) redm[wv] = mx;
    __syncthreads();
    mx = fmaxf(fmaxf(redm[0], redm[1]), fmaxf(redm[2], redm[3]));

    float e[8], sum = 0.f;
    #pragma unroll
    for (int u = 0; u < 8; ++u) {
        const int j = tid + u * 256;
        e[u] = (j <= row) ? exp2f((v[u] - mx) * kfac) : 0.f;
        sum += e[u];
    }
    #pragma unroll
    for (int o = 32; o; o >>= 1) sum += __shfl_xor(sum, o);
    __shared__ float reds[4];
    if (lane == 0) reds[wv] = sum;
    __syncthreads();
    sum = reds[0] + reds[1] + reds[2] + reds[3];
    const float inv = 1.f / sum;

    #pragma unroll
    for (int u = 0; u < 8; ++u) {
        const int j = tid + u * 256;
        Pr[j] = f2bf(e[u] * inv);
    }
}

extern "C" void kernel_launch(void* const* d_in, const int* in_sizes, int n_in,
                              void* d_out, int out_size, void* d_ws, size_t ws_size,
                              hipStream_t stream)
{
    const int B = 4, T = 2048, D = 1024;
    const float* x  = (const float*)d_in[0];
    const float* Wq = (const float*)d_in[1];
    const float* Wk = (const float*)d_in[2];
    const float* Wv = (const float*)d_in[3];
    float* out = (float*)d_out;

    const size_t nX = (size_t)B * T * D;           // 8.39M elems
    u16* Xb = (u16*)d_ws;                          // [B*T, D] bf16
    u16* Wt = Xb + nX;                             // 3 x [D, D] bf16 (transposed)
    u16* Q  = Wt + 3 * (size_t)D * D;              // [B*T, D] bf16
    u16* Kb = Q + nX;
    u16* Vb = Kb + nX;
    char* rest = (char*)(Vb + nX);
    const size_t fixed   = (size_t)((char*)rest - (char*)d_ws);
    const size_t perb_S  = (size_t)T * T * 4;
    const size_t perb_P  = (size_t)T * T * 2;
    const size_t perb_Vt = (size_t)D * T * 2;
    const bool full = ws_size >= fixed + (size_t)B * (perb_S + perb_P + perb_Vt);
    const int nb = full ? B : 1;
    float* S  = (float*)rest;
    u16*   P  = (u16*)(rest + nb * perb_S);
    u16*   Vt = (u16*)(rest + nb * (perb_S + perb_P));

    const float kfac = 1.4426950408889634f / 32.0f;  // log2(e)/sqrt(d_out)

    // 1. casts
    cast_x<<<dim3((unsigned)(nX / (8 * 256))), 256, 0, stream>>>(x, Xb, (long long)nX);
    castT_w<<<dim3(D / 32, D / 32), 256, 0, stream>>>(Wq, Wt,                     D, D);
    castT_w<<<dim3(D / 32, D / 32), 256, 0, stream>>>(Wk, Wt + (size_t)D * D,     D, D);
    castT_w<<<dim3(D / 32, D / 32), 256, 0, stream>>>(Wv, Wt + 2 * (size_t)D * D, D, D);

    // 2. QKV projections: [8192,1024] x [1024,1024]^T -> bf16
    dim3 gq(D / BN, (B * T) / BM, 1);
    gemm_bt<true, false, false><<<gq, 256, 0, stream>>>(Xb, 0, Wt,                     0, Q,  0, B * T, D, D, 1.0f);
    gemm_bt<true, false, false><<<gq, 256, 0, stream>>>(Xb, 0, Wt + (size_t)D * D,     0, Kb, 0, B * T, D, D, 1.0f);
    gemm_bt<true, false, false><<<gq, 256, 0, stream>>>(Xb, 0, Wt + 2 * (size_t)D * D, 0, Vb, 0, B * T, D, D, 1.0f);

    if (full) {
        gemm_bt<false, true, false><<<dim3(T / BN, T / BM, B), 256, 0, stream>>>(
            Q, (long long)T * D, Kb, (long long)T * D, S, (long long)T * T, T, T, D, 1.0f);
        softmax_causal<<<dim3(T, B), 256, 0, stream>>>(S, (long long)T * T, P, (long long)T * T, T, kfac);
        transpose_b<<<dim3(D / 32, T / 32, B), 256, 0, stream>>>(
            Vb, (long long)T * D, Vt, (long long)D * T, T, D);
        gemm_bt<false, false, true><<<dim3(D / BN, T / BM, B), 256, 0, stream>>>(
            P, (long long)T * T, Vt, (long long)D * T, out, (long long)T * D, T, D, T, 1.0f);
    } else {
        for (int b = 0; b < B; ++b) {
            const size_t ob = (size_t)b * T * D;
            gemm_bt<false, true, false><<<dim3(T / BN, T / BM, 1), 256, 0, stream>>>(
                Q + ob, 0, Kb + ob, 0, S, 0, T, T, D, 1.0f);
            softmax_causal<<<dim3(T, 1), 256, 0, stream>>>(S, 0, P, 0, T, kfac);
            transpose_b<<<dim3(D / 32, T / 32, 1), 256, 0, stream>>>(Vb + ob, 0, Vt, 0, T, D);
            gemm_bt<false, false, true><<<dim3(D / BN, T / BM, 1), 256, 0, stream>>>(
                P, 0, Vt, 0, out + ob, 0, T, D, T, 1.0f);
        }
    }
}

// Round 2
// 293.980 us; speedup vs baseline: 1.1237x; 1.1237x over previous
//
#include <hip/hip_runtime.h>
#include <stdint.h>
#include <math.h>

typedef unsigned short u16;
typedef __bf16 bf16x8 __attribute__((ext_vector_type(8)));
typedef float f32x4 __attribute__((ext_vector_type(4)));

#define BM 128
#define BN 128
#define BK 32

// fp32 -> bf16 round-to-nearest-even, bit-level
__device__ __forceinline__ u16 f2bf(float f) {
    union { float f; unsigned int u; } a; a.f = f;
    unsigned int u = a.u;
    u += 0x7FFFu + ((u >> 16) & 1u);
    return (u16)(u >> 16);
}
__device__ __forceinline__ float bf2f(u16 x) {
    union { unsigned int u; float f; } a; a.u = ((unsigned int)x) << 16;
    return a.f;
}

__device__ __forceinline__ void async_load16(const void* g, void* l) {
    __builtin_amdgcn_global_load_lds(
        (const __attribute__((address_space(1))) void*)g,
        (__attribute__((address_space(3))) void*)l,
        16, 0, 0);
}

// ---------------------------------------------------------------------------
// C[M,N] = A[M,K] * Bt[N,K]^T  (bf16 in, fp32 acc). m97-style structure.
// OUT_BF16: store bf16. TRI: grid.x is a linear index over the 136
// lower-triangular 128x128 blocks (S=QK^T causal). CKLIM: limit K-loop to
// causal extent (O=P*V^T). QKV_SPLIT: C cols [0,3072) scatter to 3 buffers
// of width 1024 each (Q,K,V contiguous, sCb = per-buffer elem stride).
// ---------------------------------------------------------------------------
template<bool OUT_BF16, bool TRI, bool CKLIM, bool QKV_SPLIT>
__global__ __launch_bounds__(256)
void gemm_bt(const u16* __restrict__ A, long long sAb,
             const u16* __restrict__ Bt, long long sBb,
             void* __restrict__ Cv, long long sCb,
             int M, int N, int K, float scale)
{
    int bm, bn;
    if (TRI) {
        const int idx = blockIdx.x;
        bm = (int)((sqrtf(8.f * idx + 1.f) - 1.f) * 0.5f);
        while ((bm + 1) * (bm + 2) / 2 <= idx) ++bm;
        while (bm * (bm + 1) / 2 > idx) --bm;
        bn = idx - bm * (bm + 1) / 2;
    } else {
        bn = blockIdx.x; bm = blockIdx.y;
    }
    const int bz = blockIdx.z;
    A  += (size_t)bz * sAb;
    Bt += (size_t)bz * sBb;

    const int tid  = threadIdx.x;
    const int lane = tid & 63;
    const int wv   = tid >> 6;        // wave 0..3
    const int wm   = wv >> 1;         // wave row (0..1)
    const int wn   = wv & 1;          // wave col (0..1)

    __shared__ __attribute__((aligned(16))) u16 As[BM * BK];
    __shared__ __attribute__((aligned(16))) u16 Bs[BN * BK];

    f32x4 acc[4][4] = {};

    const int rowA0 = bm * BM, rowB0 = bn * BN;
    // global_load_lds staging: wave wv covers chunks {2*wv, 2*wv+1}; each chunk
    // = 1KB = 64 lanes x 16B. Flat LDS elem (chunk*512 + lane*8) -> row-major
    // [128][32]: row = chunk*16 + lane/4, col = (lane&3)*8.
    const int srow = lane >> 2;
    const int scol = (lane & 3) * 8;

    int kEnd = K;
    if (CKLIM) { int ke = (bm + 1) * BM; kEnd = ke < K ? ke : K; }

    const int lm   = lane & 15;       // MFMA m/n index
    const int quad = lane >> 4;       // MFMA k-group
    const int lk   = quad * 8;

    for (int k0 = 0; k0 < kEnd; k0 += BK) {
        #pragma unroll
        for (int c = 0; c < 2; ++c) {
            const int cc = wv * 2 + c;
            const int r  = cc * 16 + srow;
            async_load16(&A [(size_t)(rowA0 + r) * K + k0 + scol], &As[cc * 512 + lane * 8]);
            async_load16(&Bt[(size_t)(rowB0 + r) * K + k0 + scol], &Bs[cc * 512 + lane * 8]);
        }
        __syncthreads();

        bf16x8 af[4], bfr[4];
        #pragma unroll
        for (int i = 0; i < 4; ++i)
            af[i] = *reinterpret_cast<const bf16x8*>(&As[(wm * 64 + i * 16 + lm) * BK + lk]);
        #pragma unroll
        for (int j = 0; j < 4; ++j)
            bfr[j] = *reinterpret_cast<const bf16x8*>(&Bs[(wn * 64 + j * 16 + lm) * BK + lk]);
        #pragma unroll
        for (int i = 0; i < 4; ++i)
            #pragma unroll
            for (int j = 0; j < 4; ++j)
                acc[i][j] = __builtin_amdgcn_mfma_f32_16x16x32_bf16(af[i], bfr[j], acc[i][j], 0, 0, 0);
        __syncthreads();
    }

    // Epilogue. C/D layout (m89-verified): col = lane&15, row = quad*4 + reg.
    if (OUT_BF16) {
        u16* C;
        int ldc, cmask;
        if (QKV_SPLIT) {
            C = (u16*)Cv + (size_t)(bn >> 3) * sCb;  // bn 0-7:Q, 8-15:K, 16-23:V
            ldc = 1024; cmask = 1023;
        } else {
            C = (u16*)Cv + (size_t)bz * sCb;
            ldc = N; cmask = ~0;
        }
        #pragma unroll
        for (int i = 0; i < 4; ++i)
            #pragma unroll
            for (int j = 0; j < 4; ++j) {
                const int r0 = rowA0 + wm * 64 + i * 16 + quad * 4;
                const int c0 = (rowB0 + wn * 64 + j * 16 + lm) & cmask;
                #pragma unroll
                for (int g = 0; g < 4; ++g)
                    C[(size_t)(r0 + g) * ldc + c0] = f2bf(acc[i][j][g] * scale);
            }
    } else {
        float* C = (float*)Cv + (size_t)bz * sCb;
        #pragma unroll
        for (int i = 0; i < 4; ++i)
            #pragma unroll
            for (int j = 0; j < 4; ++j) {
                const int r0 = rowA0 + wm * 64 + i * 16 + quad * 4;
                const int c0 = rowB0 + wn * 64 + j * 16 + lm;
                #pragma unroll
                for (int g = 0; g < 4; ++g)
                    C[(size_t)(r0 + g) * N + c0] = acc[i][j][g] * scale;
            }
    }
}

// x fp32 -> bf16, 8 elems/thread
__global__ __launch_bounds__(256)
void cast_x(const float* __restrict__ x, u16* __restrict__ o, long long n)
{
    long long i = ((long long)blockIdx.x * blockDim.x + threadIdx.x) * 8;
    if (i >= n) return;
    const float4 a = *(const float4*)(x + i);
    const float4 b = *(const float4*)(x + i + 4);
    union { u16 u[8]; float4 v; } r;
    r.u[0] = f2bf(a.x); r.u[1] = f2bf(a.y); r.u[2] = f2bf(a.z); r.u[3] = f2bf(a.w);
    r.u[4] = f2bf(b.x); r.u[5] = f2bf(b.y); r.u[6] = f2bf(b.z); r.u[7] = f2bf(b.w);
    *(float4*)(o + i) = r.v;
}

// W[rows][cols] fp32 -> Wt[cols][rows] bf16 (LDS tile transpose, +1 pad)
__global__ __launch_bounds__(256)
void castT_w(const float* __restrict__ W, u16* __restrict__ Wt, int rows, int cols)
{
    __shared__ u16 t[32][33];
    const int c0 = blockIdx.x * 32, r0 = blockIdx.y * 32;
    const int tx = threadIdx.x & 31, ty = threadIdx.x >> 5;  // ty 0..7
    #pragma unroll
    for (int s = 0; s < 32; s += 8)
        t[ty + s][tx] = f2bf(W[(size_t)(r0 + ty + s) * cols + c0 + tx]);
    __syncthreads();
    #pragma unroll
    for (int s = 0; s < 32; s += 8)
        Wt[(size_t)(c0 + ty + s) * rows + r0 + tx] = t[tx][ty + s];
}

// V[rows][cols] bf16 -> Vt[cols][rows] bf16, batched via blockIdx.z
__global__ __launch_bounds__(256)
void transpose_b(const u16* __restrict__ V, long long sVb,
                 u16* __restrict__ Vt, long long sVtb, int rows, int cols)
{
    V  += (size_t)blockIdx.z * sVb;
    Vt += (size_t)blockIdx.z * sVtb;
    __shared__ u16 t[32][33];
    const int c0 = blockIdx.x * 32, r0 = blockIdx.y * 32;
    const int tx = threadIdx.x & 31, ty = threadIdx.x >> 5;
    #pragma unroll
    for (int s = 0; s < 32; s += 8)
        t[ty + s][tx] = V[(size_t)(r0 + ty + s) * cols + c0 + tx];
    __syncthreads();
    #pragma unroll
    for (int s = 0; s < 32; s += 8)
        Vt[(size_t)(c0 + ty + s) * rows + r0 + tx] = t[tx][ty + s];
}

// Causal row softmax over bf16 scores: P[i][j] = softmax_{j<=i}(S[i][:]*kfac),
// P[i][j>i] = 0. One 256-thread block per row; T=2048 (8 contiguous elems/thr).
__global__ __launch_bounds__(256)
void softmax_causal(const u16* __restrict__ S, long long sSb,
                    u16* __restrict__ P, long long sPb, int T, float kfac)
{
    const int row = blockIdx.x, bz = blockIdx.y;
    const u16* Sr = S + (size_t)bz * sSb + (size_t)row * T;
    u16*       Pr = P + (size_t)bz * sPb + (size_t)row * T;
    const int tid = threadIdx.x, lane = tid & 63, wv = tid >> 6;
    const int j0 = tid * 8;

    union { u16 u[8]; float4 v; } in;
    in.v = *(const float4*)(Sr + j0);   // may cover unwritten cols; masked below

    float v[8];
    float mx = -1e30f;
    #pragma unroll
    for (int u = 0; u < 8; ++u) {
        const int j = j0 + u;
        v[u] = (j <= row) ? bf2f(in.u[u]) : -1e30f;
        mx = fmaxf(mx, v[u]);
    }
    #pragma unroll
    for (int o = 32; o; o >>= 1) mx = fmaxf(mx, __shfl_xor(mx, o));
    __shared__ float redm[4];
    if (lane == 0) redm[wv] = mx;
    __syncthreads();
    mx = fmaxf(fmaxf(redm[0], redm[1]), fmaxf(redm[2], redm[3]));

    float e[8], sum = 0.f;
    #pragma unroll
    for (int u = 0; u < 8; ++u) {
        const int j = j0 + u;
        e[u] = (j <= row) ? exp2f((v[u] - mx) * kfac) : 0.f;
        sum += e[u];
    }
    #pragma unroll
    for (int o = 32; o; o >>= 1) sum += __shfl_xor(sum, o);
    __shared__ float reds[4];
    if (lane == 0) reds[wv] = sum;
    __syncthreads();
    sum = reds[0] + reds[1] + reds[2] + reds[3];
    const float inv = 1.f / sum;

    union { u16 u[8]; float4 v; } r;
    #pragma unroll
    for (int u = 0; u < 8; ++u) r.u[u] = f2bf(e[u] * inv);
    *(float4*)(Pr + j0) = r.v;
}

extern "C" void kernel_launch(void* const* d_in, const int* in_sizes, int n_in,
                              void* d_out, int out_size, void* d_ws, size_t ws_size,
                              hipStream_t stream)
{
    const int B = 4, T = 2048, D = 1024;
    const float* x  = (const float*)d_in[0];
    const float* Wq = (const float*)d_in[1];
    const float* Wk = (const float*)d_in[2];
    const float* Wv = (const float*)d_in[3];
    float* out = (float*)d_out;

    const size_t nX = (size_t)B * T * D;           // 8.39M elems
    u16* Xb = (u16*)d_ws;                          // [B*T, D] bf16
    u16* Wt = Xb + nX;                             // 3 x [D, D] bf16 (transposed, concat)
    u16* Q  = Wt + 3 * (size_t)D * D;              // [B*T, D] bf16  (Q,K,V contiguous)
    u16* Kb = Q + nX;
    u16* Vb = Kb + nX;
    char* rest = (char*)(Vb + nX);
    const size_t fixed   = (size_t)((char*)rest - (char*)d_ws);
    const size_t perb_S  = (size_t)T * T * 2;      // bf16 now
    const size_t perb_P  = (size_t)T * T * 2;
    const size_t perb_Vt = (size_t)D * T * 2;
    const bool full = ws_size >= fixed + (size_t)B * (perb_S + perb_P + perb_Vt);
    const int nb = full ? B : 1;
    u16* S  = (u16*)rest;
    u16* P  = S + nb * (size_t)T * T;
    u16* Vt = P + nb * (size_t)T * T;

    const float kfac = 1.4426950408889634f / 32.0f;  // log2(e)/sqrt(d_out)
    const int nTri = (T / BM) * (T / BM + 1) / 2;    // 136 causal blocks

    // 1. casts
    cast_x<<<dim3((unsigned)(nX / (8 * 256))), 256, 0, stream>>>(x, Xb, (long long)nX);
    castT_w<<<dim3(D / 32, D / 32), 256, 0, stream>>>(Wq, Wt,                     D, D);
    castT_w<<<dim3(D / 32, D / 32), 256, 0, stream>>>(Wk, Wt + (size_t)D * D,     D, D);
    castT_w<<<dim3(D / 32, D / 32), 256, 0, stream>>>(Wv, Wt + 2 * (size_t)D * D, D, D);

    // 2. Merged QKV projection: [8192,1024] x [1024,3072]^T -> Q|K|V bf16
    gemm_bt<true, false, false, true><<<dim3(3 * D / BN, (B * T) / BM, 1), 256, 0, stream>>>(
        Xb, 0, Wt, 0, Q, (long long)nX, B * T, 3 * D, D, 1.0f);

    if (full) {
        // 3. S = Q K^T (bf16 out), only the 136 lower-tri blocks per batch
        gemm_bt<true, true, false, false><<<dim3(nTri, 1, B), 256, 0, stream>>>(
            Q, (long long)T * D, Kb, (long long)T * D, S, (long long)T * T, T, T, D, 1.0f);
        // 4. causal softmax -> P bf16
        softmax_causal<<<dim3(T, B), 256, 0, stream>>>(S, (long long)T * T, P, (long long)T * T, T, kfac);
        // 5. V^T
        transpose_b<<<dim3(D / 32, T / 32, B), 256, 0, stream>>>(
            Vb, (long long)T * D, Vt, (long long)D * T, T, D);
        // 6. O = P V^T (fp32 out), K-loop limited to causal extent
        gemm_bt<false, false, true, false><<<dim3(D / BN, T / BM, B), 256, 0, stream>>>(
            P, (long long)T * T, Vt, (long long)D * T, out, (long long)T * D, T, D, T, 1.0f);
    } else {
        for (int b = 0; b < B; ++b) {
            const size_t ob = (size_t)b * T * D;
            gemm_bt<true, true, false, false><<<dim3(nTri, 1, 1), 256, 0, stream>>>(
                Q + ob, 0, Kb + ob, 0, S, 0, T, T, D, 1.0f);
            softmax_causal<<<dim3(T, 1), 256, 0, stream>>>(S, 0, P, 0, T, kfac);
            transpose_b<<<dim3(D / 32, T / 32, 1), 256, 0, stream>>>(Vb + ob, 0, Vt, 0, T, D);
            gemm_bt<false, false, true, false><<<dim3(D / BN, T / BM, 1), 256, 0, stream>>>(
                P, 0, Vt, 0, out + ob, 0, T, D, T, 1.0f);
        }
    }
}

// Round 3
// 275.466 us; speedup vs baseline: 1.1992x; 1.0672x over previous
//
#include <hip/hip_runtime.h>
#include <stdint.h>
#include <math.h>

typedef unsigned short u16;
typedef __bf16 bf16x8 __attribute__((ext_vector_type(8)));
typedef float f32x4 __attribute__((ext_vector_type(4)));

#define BM 128
#define BN 128
#define BK 32

enum { M_QKV = 0, M_SCORE = 1, M_PV = 2 };

// fp32 -> bf16 round-to-nearest-even, bit-level
__device__ __forceinline__ u16 f2bf(float f) {
    union { float f; unsigned int u; } a; a.f = f;
    unsigned int u = a.u;
    u += 0x7FFFu + ((u >> 16) & 1u);
    return (u16)(u >> 16);
}

__device__ __forceinline__ void async_load16(const void* g, void* l) {
    __builtin_amdgcn_global_load_lds(
        (const __attribute__((address_space(1))) void*)g,
        (__attribute__((address_space(3))) void*)l,
        16, 0, 0);
}

// ---------------------------------------------------------------------------
// C[M,N] = A[M,K] * Bt[N,K]^T  (bf16 in, fp32 acc), m97-style 128x128 tile.
// LDS XOR swizzle: 16B granule (row, q) of the [128][32] tile is stored at
// slot q ^ ((row>>1)&3) within its 64B row. Staging permutes the *global
// source column* per lane (LDS side of global_load_lds must stay lane-linear);
// fragment ds_read_b128 then lands 2-way max on banks (free per m136).
//
// M_QKV : C cols [0,3N') scatter to 3 bf16 buffers of width 1024 (Q|K|V).
// M_SCORE: grid.x = linear index over lower-tri 128x128 blocks; epilogue
//          writes E = exp2(acc*kfac) bf16 (causal-masked) and atomically
//          accumulates per-row sum-of-exp into rowsum[bz*M + r].
// M_PV  : K-loop limited to causal extent; epilogue scales rows by
//          1/rowsum[r], stores fp32.
// ---------------------------------------------------------------------------
template<int MODE>
__global__ __launch_bounds__(256)
void gemm_bt(const u16* __restrict__ A, long long sAb,
             const u16* __restrict__ Bt, long long sBb,
             void* __restrict__ Cv, long long sCb,
             float* __restrict__ rowsum,
             int M, int N, int K, float kfac)
{
    int bm, bn;
    if (MODE == M_SCORE) {
        const int idx = blockIdx.x;
        bm = (int)((sqrtf(8.f * idx + 1.f) - 1.f) * 0.5f);
        while ((bm + 1) * (bm + 2) / 2 <= idx) ++bm;
        while (bm * (bm + 1) / 2 > idx) --bm;
        bn = idx - bm * (bm + 1) / 2;
    } else {
        bn = blockIdx.x; bm = blockIdx.y;
    }
    const int bz = blockIdx.z;
    A  += (size_t)bz * sAb;
    Bt += (size_t)bz * sBb;

    const int tid  = threadIdx.x;
    const int lane = tid & 63;
    const int wv   = tid >> 6;        // wave 0..3
    const int wm   = wv >> 1;         // wave row (0..1)
    const int wn   = wv & 1;          // wave col (0..1)

    __shared__ __attribute__((aligned(16))) u16 As[BM * BK];
    __shared__ __attribute__((aligned(16))) u16 Bs[BN * BK];

    f32x4 acc[4][4] = {};

    const int rowA0 = bm * BM, rowB0 = bn * BN;
    // Staging: chunk cc = rows [cc*16, cc*16+16); lane s -> LDS elem
    // cc*512 + s*8 = (row = cc*16 + s/4, slot = s&3). That slot holds global
    // granule c = (s&3) ^ ((s>>3)&3)  [since (row>>1)&3 == (s>>3)&3].
    const int srow = lane >> 2;
    const int scol = (((lane & 3) ^ ((lane >> 3) & 3)) * 8);

    int kEnd = K;
    if (MODE == M_PV) { int ke = (bm + 1) * BM; kEnd = ke < K ? ke : K; }

    const int lm   = lane & 15;       // MFMA m/n index
    const int quad = lane >> 4;       // MFMA k-group
    const int lk   = (quad ^ ((lm >> 1) & 3)) * 8;  // swizzled k-slot

    for (int k0 = 0; k0 < kEnd; k0 += BK) {
        #pragma unroll
        for (int c = 0; c < 2; ++c) {
            const int cc = wv * 2 + c;
            const int r  = cc * 16 + srow;
            async_load16(&A [(size_t)(rowA0 + r) * K + k0 + scol], &As[cc * 512 + lane * 8]);
            async_load16(&Bt[(size_t)(rowB0 + r) * K + k0 + scol], &Bs[cc * 512 + lane * 8]);
        }
        __syncthreads();

        bf16x8 af[4], bfr[4];
        #pragma unroll
        for (int i = 0; i < 4; ++i)
            af[i] = *reinterpret_cast<const bf16x8*>(&As[(wm * 64 + i * 16 + lm) * BK + lk]);
        #pragma unroll
        for (int j = 0; j < 4; ++j)
            bfr[j] = *reinterpret_cast<const bf16x8*>(&Bs[(wn * 64 + j * 16 + lm) * BK + lk]);
        #pragma unroll
        for (int i = 0; i < 4; ++i)
            #pragma unroll
            for (int j = 0; j < 4; ++j)
                acc[i][j] = __builtin_amdgcn_mfma_f32_16x16x32_bf16(af[i], bfr[j], acc[i][j], 0, 0, 0);
        __syncthreads();
    }

    // Epilogue. C/D layout (m89-verified): col = lane&15, row = quad*4 + reg.
    if (MODE == M_QKV) {
        u16* C = (u16*)Cv + (size_t)(bn >> 3) * sCb;  // bn 0-7:Q, 8-15:K, 16-23:V
        #pragma unroll
        for (int i = 0; i < 4; ++i)
            #pragma unroll
            for (int j = 0; j < 4; ++j) {
                const int r0 = rowA0 + wm * 64 + i * 16 + quad * 4;
                const int c0 = (rowB0 + wn * 64 + j * 16 + lm) & 1023;
                #pragma unroll
                for (int g = 0; g < 4; ++g)
                    C[(size_t)(r0 + g) * 1024 + c0] = f2bf(acc[i][j][g]);
            }
    } else if (MODE == M_SCORE) {
        u16* E = (u16*)Cv + (size_t)bz * sCb;
        float rs[4][4];   // [i][g] partial row sums (cols of this block)
        #pragma unroll
        for (int i = 0; i < 4; ++i)
            #pragma unroll
            for (int g = 0; g < 4; ++g) rs[i][g] = 0.f;
        #pragma unroll
        for (int i = 0; i < 4; ++i)
            #pragma unroll
            for (int j = 0; j < 4; ++j) {
                const int r0 = rowA0 + wm * 64 + i * 16 + quad * 4;
                const int c  = rowB0 + wn * 64 + j * 16 + lm;
                #pragma unroll
                for (int g = 0; g < 4; ++g) {
                    const int r = r0 + g;
                    float e = (c <= r) ? exp2f(acc[i][j][g] * kfac) : 0.f;
                    E[(size_t)r * N + c] = f2bf(e);
                    rs[i][g] += e;
                }
            }
        // reduce across the 16 lm lanes (xor masks stay inside the quad group)
        #pragma unroll
        for (int i = 0; i < 4; ++i)
            #pragma unroll
            for (int g = 0; g < 4; ++g) {
                float v = rs[i][g];
                v += __shfl_xor(v, 1); v += __shfl_xor(v, 2);
                v += __shfl_xor(v, 4); v += __shfl_xor(v, 8);
                rs[i][g] = v;
            }
        if (lm == 0) {
            #pragma unroll
            for (int i = 0; i < 4; ++i)
                #pragma unroll
                for (int g = 0; g < 4; ++g) {
                    const int r = rowA0 + wm * 64 + i * 16 + quad * 4 + g;
                    atomicAdd(&rowsum[(size_t)bz * M + r], rs[i][g]);
                }
        }
    } else {  // M_PV
        float* C = (float*)Cv + (size_t)bz * sCb;
        #pragma unroll
        for (int i = 0; i < 4; ++i) {
            const int r0 = rowA0 + wm * 64 + i * 16 + quad * 4;
            float inv[4];
            #pragma unroll
            for (int g = 0; g < 4; ++g)
                inv[g] = 1.f / rowsum[(size_t)bz * M + r0 + g];
            #pragma unroll
            for (int j = 0; j < 4; ++j) {
                const int c0 = rowB0 + wn * 64 + j * 16 + lm;
                #pragma unroll
                for (int g = 0; g < 4; ++g)
                    C[(size_t)(r0 + g) * N + c0] = acc[i][j][g] * inv[g];
            }
        }
    }
}

// x fp32 -> bf16, 8 elems/thread
__global__ __launch_bounds__(256)
void cast_x(const float* __restrict__ x, u16* __restrict__ o, long long n)
{
    long long i = ((long long)blockIdx.x * blockDim.x + threadIdx.x) * 8;
    if (i >= n) return;
    const float4 a = *(const float4*)(x + i);
    const float4 b = *(const float4*)(x + i + 4);
    union { u16 u[8]; float4 v; } r;
    r.u[0] = f2bf(a.x); r.u[1] = f2bf(a.y); r.u[2] = f2bf(a.z); r.u[3] = f2bf(a.w);
    r.u[4] = f2bf(b.x); r.u[5] = f2bf(b.y); r.u[6] = f2bf(b.z); r.u[7] = f2bf(b.w);
    *(float4*)(o + i) = r.v;
}

// W[rows][cols] fp32 -> Wt[cols][rows] bf16 (LDS tile transpose, +1 pad)
__global__ __launch_bounds__(256)
void castT_w(const float* __restrict__ W, u16* __restrict__ Wt, int rows, int cols)
{
    __shared__ u16 t[32][33];
    const int c0 = blockIdx.x * 32, r0 = blockIdx.y * 32;
    const int tx = threadIdx.x & 31, ty = threadIdx.x >> 5;  // ty 0..7
    #pragma unroll
    for (int s = 0; s < 32; s += 8)
        t[ty + s][tx] = f2bf(W[(size_t)(r0 + ty + s) * cols + c0 + tx]);
    __syncthreads();
    #pragma unroll
    for (int s = 0; s < 32; s += 8)
        Wt[(size_t)(c0 + ty + s) * rows + r0 + tx] = t[tx][ty + s];
}

// V[rows][cols] bf16 -> Vt[cols][rows] bf16, batched via blockIdx.z
__global__ __launch_bounds__(256)
void transpose_b(const u16* __restrict__ V, long long sVb,
                 u16* __restrict__ Vt, long long sVtb, int rows, int cols)
{
    V  += (size_t)blockIdx.z * sVb;
    Vt += (size_t)blockIdx.z * sVtb;
    __shared__ u16 t[32][33];
    const int c0 = blockIdx.x * 32, r0 = blockIdx.y * 32;
    const int tx = threadIdx.x & 31, ty = threadIdx.x >> 5;
    #pragma unroll
    for (int s = 0; s < 32; s += 8)
        t[ty + s][tx] = V[(size_t)(r0 + ty + s) * cols + c0 + tx];
    __syncthreads();
    #pragma unroll
    for (int s = 0; s < 32; s += 8)
        Vt[(size_t)(c0 + ty + s) * rows + r0 + tx] = t[tx][ty + s];
}

extern "C" void kernel_launch(void* const* d_in, const int* in_sizes, int n_in,
                              void* d_out, int out_size, void* d_ws, size_t ws_size,
                              hipStream_t stream)
{
    const int B = 4, T = 2048, D = 1024;
    const float* x  = (const float*)d_in[0];
    const float* Wq = (const float*)d_in[1];
    const float* Wk = (const float*)d_in[2];
    const float* Wv = (const float*)d_in[3];
    float* out = (float*)d_out;

    const size_t nX = (size_t)B * T * D;           // 8.39M elems
    u16* Xb = (u16*)d_ws;                          // [B*T, D] bf16
    u16* Wt = Xb + nX;                             // 3 x [D, D] bf16 (transposed, concat)
    u16* Q  = Wt + 3 * (size_t)D * D;              // [B*T, D] bf16  (Q,K,V contiguous)
    u16* Kb = Q + nX;
    u16* Vb = Kb + nX;
    char* rest = (char*)(Vb + nX);
    const size_t fixed   = (size_t)((char*)rest - (char*)d_ws);
    const size_t perb_E  = (size_t)T * T * 2;
    const size_t perb_Vt = (size_t)D * T * 2;
    const size_t perb_rs = (size_t)T * 4;
    const bool full = ws_size >= fixed + (size_t)B * (perb_E + perb_Vt + perb_rs);
    const int nb = full ? B : 1;
    u16*   E  = (u16*)rest;
    u16*   Vt = E + nb * (size_t)T * T;
    float* RS = (float*)(Vt + nb * (size_t)D * T);

    const float kfac = 1.4426950408889634f / 32.0f;  // log2(e)/sqrt(d_out)
    const int nTri = (T / BM) * (T / BM + 1) / 2;    // 136 causal blocks

    // 1. casts
    cast_x<<<dim3((unsigned)(nX / (8 * 256))), 256, 0, stream>>>(x, Xb, (long long)nX);
    castT_w<<<dim3(D / 32, D / 32), 256, 0, stream>>>(Wq, Wt,                     D, D);
    castT_w<<<dim3(D / 32, D / 32), 256, 0, stream>>>(Wk, Wt + (size_t)D * D,     D, D);
    castT_w<<<dim3(D / 32, D / 32), 256, 0, stream>>>(Wv, Wt + 2 * (size_t)D * D, D, D);

    // 2. Merged QKV projection: [8192,1024] x [1024,3072]^T -> Q|K|V bf16
    gemm_bt<M_QKV><<<dim3(3 * D / BN, (B * T) / BM, 1), 256, 0, stream>>>(
        Xb, 0, Wt, 0, Q, (long long)nX, nullptr, B * T, 3 * D, D, 0.f);

    if (full) {
        hipMemsetAsync(RS, 0, (size_t)B * T * 4, stream);
        // 3. E = exp2(kfac * Q K^T) bf16 (causal), rowsum accumulated
        gemm_bt<M_SCORE><<<dim3(nTri, 1, B), 256, 0, stream>>>(
            Q, (long long)T * D, Kb, (long long)T * D, E, (long long)T * T, RS, T, T, D, kfac);
        // 4. V^T
        transpose_b<<<dim3(D / 32, T / 32, B), 256, 0, stream>>>(
            Vb, (long long)T * D, Vt, (long long)D * T, T, D);
        // 5. O = (E V^T) / rowsum (fp32 out), K-loop to causal extent
        gemm_bt<M_PV><<<dim3(D / BN, T / BM, B), 256, 0, stream>>>(
            E, (long long)T * T, Vt, (long long)D * T, out, (long long)T * D, RS, T, D, T, 0.f);
    } else {
        for (int b = 0; b < B; ++b) {
            const size_t ob = (size_t)b * T * D;
            hipMemsetAsync(RS, 0, (size_t)T * 4, stream);
            gemm_bt<M_SCORE><<<dim3(nTri, 1, 1), 256, 0, stream>>>(
                Q + ob, 0, Kb + ob, 0, E, 0, RS, T, T, D, kfac);
            transpose_b<<<dim3(D / 32, T / 32, 1), 256, 0, stream>>>(Vb + ob, 0, Vt, 0, T, D);
            gemm_bt<M_PV><<<dim3(D / BN, T / BM, 1), 256, 0, stream>>>(
                E, 0, Vt, 0, out + ob, 0, RS, T, D, T, 0.f);
        }
    }
}

// Round 4
// 267.155 us; speedup vs baseline: 1.2365x; 1.0311x over previous
//
#include <hip/hip_runtime.h>
#include <stdint.h>
#include <math.h>

typedef unsigned short u16;
typedef __bf16 bf16x8 __attribute__((ext_vector_type(8)));
typedef float f32x4 __attribute__((ext_vector_type(4)));

#define BK 32

enum { M_QKV = 0, M_SCORE = 1, M_PV = 2 };

// fp32 -> bf16 round-to-nearest-even, bit-level
__device__ __forceinline__ u16 f2bf(float f) {
    union { float f; unsigned int u; } a; a.f = f;
    unsigned int u = a.u;
    u += 0x7FFFu + ((u >> 16) & 1u);
    return (u16)(u >> 16);
}

__device__ __forceinline__ void async_load16(const void* g, void* l) {
    __builtin_amdgcn_global_load_lds(
        (const __attribute__((address_space(1))) void*)g,
        (__attribute__((address_space(3))) void*)l,
        16, 0, 0);
}

// ---------------------------------------------------------------------------
// C[M,N] = A[M,K] * Bt[N,K]^T (bf16 in, fp32 acc), TBMxTBN tile, 4 waves 2x2.
// LDS XOR swizzle (verified R3: conflicts 6.29M -> 0): granule (row,q) lives
// at slot q ^ ((row>>1)&3); staging permutes the global source column.
//
// M_QKV  (128x128): bn 0-7 -> Q, 8-15 -> K (row-major); bn 16-23 -> V written
//         TRANSPOSED into vt[b][c][t] with packed 8B stores (acc regs are
//         contiguous in t in the transposed layout).
// M_SCORE (64x128): grid.x = linear lower-tri index (row-tile bm has bm/2+1
//         col-tiles); epilogue writes E=exp2(acc*kfac) bf16 causal-masked and
//         atomically accumulates per-row sum-of-exp.
// M_PV   (64x128): K-loop to causal extent (bm+1)*TBM; scales by 1/rowsum.
// ---------------------------------------------------------------------------
template<int MODE, int TBM, int TBN>
__global__ __launch_bounds__(256)
void gemm_bt(const u16* __restrict__ A, long long sAb,
             const u16* __restrict__ Bt, long long sBb,
             void* __restrict__ Cv, long long sCb,
             float* __restrict__ rowsum, u16* __restrict__ vt,
             int M, int N, int K, float kfac)
{
    constexpr int NI  = TBM / 32, NJ  = TBN / 32;   // frags per wave
    constexpr int ACH = TBM / 64, BCH = TBN / 64;   // staging chunks per wave

    int bm, bn;
    if (MODE == M_SCORE) {
        // row-tile 2u occupies idx [u*u+u, (u+1)^2); row 2u+1: [(u+1)^2, (u+1)^2+u+1)
        const int idx = blockIdx.x;
        int w = (int)sqrtf((float)idx + 0.5f);
        while (w * w > idx) --w;
        while ((w + 1) * (w + 1) <= idx) ++w;
        if (idx < w * w + w) { bm = 2 * w - 1; bn = idx - w * w; }
        else                 { bm = 2 * w;     bn = idx - (w * w + w); }
    } else {
        bn = blockIdx.x; bm = blockIdx.y;
    }
    const int bz = blockIdx.z;
    A  += (size_t)bz * sAb;
    Bt += (size_t)bz * sBb;

    const int tid  = threadIdx.x;
    const int lane = tid & 63;
    const int wv   = tid >> 6;
    const int wm   = wv >> 1;         // wave row (0..1)
    const int wn   = wv & 1;          // wave col (0..1)

    __shared__ __attribute__((aligned(16))) u16 As[TBM * BK];
    __shared__ __attribute__((aligned(16))) u16 Bs[TBN * BK];

    f32x4 acc[NI][NJ] = {};

    const int rowA0 = bm * TBM, rowB0 = bn * TBN;
    // staging: chunk cc = 16 rows; lane s -> (row cc*16+s/4, slot s&3);
    // slot holds global granule (s&3) ^ ((s>>3)&3)
    const int srow = lane >> 2;
    const int scol = (((lane & 3) ^ ((lane >> 3) & 3)) * 8);

    int kEnd = K;
    if (MODE == M_PV) { int ke = (bm + 1) * TBM; kEnd = ke < K ? ke : K; }

    const int lm   = lane & 15;
    const int quad = lane >> 4;
    const int lk   = (quad ^ ((lm >> 1) & 3)) * 8;  // swizzled k-slot

    for (int k0 = 0; k0 < kEnd; k0 += BK) {
        #pragma unroll
        for (int c = 0; c < ACH; ++c) {
            const int cc = wv * ACH + c;
            const int r  = cc * 16 + srow;
            async_load16(&A[(size_t)(rowA0 + r) * K + k0 + scol], &As[cc * 512 + lane * 8]);
        }
        #pragma unroll
        for (int c = 0; c < BCH; ++c) {
            const int cc = wv * BCH + c;
            const int r  = cc * 16 + srow;
            async_load16(&Bt[(size_t)(rowB0 + r) * K + k0 + scol], &Bs[cc * 512 + lane * 8]);
        }
        __syncthreads();

        bf16x8 af[NI], bfr[NJ];
        #pragma unroll
        for (int i = 0; i < NI; ++i)
            af[i] = *reinterpret_cast<const bf16x8*>(&As[(wm * (TBM / 2) + i * 16 + lm) * BK + lk]);
        #pragma unroll
        for (int j = 0; j < NJ; ++j)
            bfr[j] = *reinterpret_cast<const bf16x8*>(&Bs[(wn * (TBN / 2) + j * 16 + lm) * BK + lk]);
        #pragma unroll
        for (int i = 0; i < NI; ++i)
            #pragma unroll
            for (int j = 0; j < NJ; ++j)
                acc[i][j] = __builtin_amdgcn_mfma_f32_16x16x32_bf16(af[i], bfr[j], acc[i][j], 0, 0, 0);
        __syncthreads();
    }

    // Epilogue. C/D layout (m89-verified): col = lane&15, row = quad*4 + reg.
    if (MODE == M_QKV) {
        if (bn < 16) {
            u16* C = (u16*)Cv + (size_t)(bn >> 3) * sCb;  // 0-7: Q, 8-15: K
            #pragma unroll
            for (int i = 0; i < NI; ++i)
                #pragma unroll
                for (int j = 0; j < NJ; ++j) {
                    const int r0 = rowA0 + wm * (TBM / 2) + i * 16 + quad * 4;
                    const int c0 = (rowB0 + wn * (TBN / 2) + j * 16 + lm) & 1023;
                    #pragma unroll
                    for (int g = 0; g < 4; ++g)
                        C[(size_t)(r0 + g) * 1024 + c0] = f2bf(acc[i][j][g]);
                }
        } else {
            // V -> Vt[b][c][t]; b = r>>11, t = r&2047; 4 regs = 4 consecutive t
            #pragma unroll
            for (int i = 0; i < NI; ++i) {
                const int r0 = rowA0 + wm * (TBM / 2) + i * 16 + quad * 4;
                const int b  = r0 >> 11, t0 = r0 & 2047;
                #pragma unroll
                for (int j = 0; j < NJ; ++j) {
                    const int c0 = (rowB0 + wn * (TBN / 2) + j * 16 + lm) & 1023;
                    ushort4 pk;
                    pk.x = f2bf(acc[i][j][0]); pk.y = f2bf(acc[i][j][1]);
                    pk.z = f2bf(acc[i][j][2]); pk.w = f2bf(acc[i][j][3]);
                    *(ushort4*)&vt[((size_t)b << 21) + ((size_t)c0 << 11) + t0] = pk;
                }
            }
        }
    } else if (MODE == M_SCORE) {
        u16* E = (u16*)Cv + (size_t)bz * sCb;
        float rs[NI][4];
        #pragma unroll
        for (int i = 0; i < NI; ++i)
            #pragma unroll
            for (int g = 0; g < 4; ++g) rs[i][g] = 0.f;
        #pragma unroll
        for (int i = 0; i < NI; ++i)
            #pragma unroll
            for (int j = 0; j < NJ; ++j) {
                const int r0 = rowA0 + wm * (TBM / 2) + i * 16 + quad * 4;
                const int c  = rowB0 + wn * (TBN / 2) + j * 16 + lm;
                #pragma unroll
                for (int g = 0; g < 4; ++g) {
                    const int r = r0 + g;
                    float e = (c <= r) ? exp2f(acc[i][j][g] * kfac) : 0.f;
                    E[(size_t)r * N + c] = f2bf(e);
                    rs[i][g] += e;
                }
            }
        #pragma unroll
        for (int i = 0; i < NI; ++i)
            #pragma unroll
            for (int g = 0; g < 4; ++g) {
                float v = rs[i][g];
                v += __shfl_xor(v, 1); v += __shfl_xor(v, 2);
                v += __shfl_xor(v, 4); v += __shfl_xor(v, 8);
                rs[i][g] = v;
            }
        if (lm == 0) {
            #pragma unroll
            for (int i = 0; i < NI; ++i)
                #pragma unroll
                for (int g = 0; g < 4; ++g) {
                    const int r = rowA0 + wm * (TBM / 2) + i * 16 + quad * 4 + g;
                    atomicAdd(&rowsum[(size_t)bz * M + r], rs[i][g]);
                }
        }
    } else {  // M_PV
        float* C = (float*)Cv + (size_t)bz * sCb;
        #pragma unroll
        for (int i = 0; i < NI; ++i) {
            const int r0 = rowA0 + wm * (TBM / 2) + i * 16 + quad * 4;
            float inv[4];
            #pragma unroll
            for (int g = 0; g < 4; ++g)
                inv[g] = 1.f / rowsum[(size_t)bz * M + r0 + g];
            #pragma unroll
            for (int j = 0; j < NJ; ++j) {
                const int c0 = rowB0 + wn * (TBN / 2) + j * 16 + lm;
                #pragma unroll
                for (int g = 0; g < 4; ++g)
                    C[(size_t)(r0 + g) * N + c0] = acc[i][j][g] * inv[g];
            }
        }
    }
}

// x fp32 -> bf16, 8 elems/thread
__global__ __launch_bounds__(256)
void cast_x(const float* __restrict__ x, u16* __restrict__ o, long long n)
{
    long long i = ((long long)blockIdx.x * blockDim.x + threadIdx.x) * 8;
    if (i >= n) return;
    const float4 a = *(const float4*)(x + i);
    const float4 b = *(const float4*)(x + i + 4);
    union { u16 u[8]; float4 v; } r;
    r.u[0] = f2bf(a.x); r.u[1] = f2bf(a.y); r.u[2] = f2bf(a.z); r.u[3] = f2bf(a.w);
    r.u[4] = f2bf(b.x); r.u[5] = f2bf(b.y); r.u[6] = f2bf(b.z); r.u[7] = f2bf(b.w);
    *(float4*)(o + i) = r.v;
}

// W[z][D][D] fp32 -> Wt[z][D][D] bf16 transposed; z selects Wq/Wk/Wv
__global__ __launch_bounds__(256)
void castT_w3(const float* __restrict__ W0, const float* __restrict__ W1,
              const float* __restrict__ W2, u16* __restrict__ Wt, int D)
{
    const float* W = blockIdx.z == 0 ? W0 : (blockIdx.z == 1 ? W1 : W2);
    u16* dst = Wt + (size_t)blockIdx.z * D * D;
    __shared__ u16 t[32][33];
    const int c0 = blockIdx.x * 32, r0 = blockIdx.y * 32;
    const int tx = threadIdx.x & 31, ty = threadIdx.x >> 5;  // ty 0..7
    #pragma unroll
    for (int s = 0; s < 32; s += 8)
        t[ty + s][tx] = f2bf(W[(size_t)(r0 + ty + s) * D + c0 + tx]);
    __syncthreads();
    #pragma unroll
    for (int s = 0; s < 32; s += 8)
        dst[(size_t)(c0 + ty + s) * D + r0 + tx] = t[tx][ty + s];
}

extern "C" void kernel_launch(void* const* d_in, const int* in_sizes, int n_in,
                              void* d_out, int out_size, void* d_ws, size_t ws_size,
                              hipStream_t stream)
{
    const int B = 4, T = 2048, D = 1024;
    const float* x  = (const float*)d_in[0];
    const float* Wq = (const float*)d_in[1];
    const float* Wk = (const float*)d_in[2];
    const float* Wv = (const float*)d_in[3];
    float* out = (float*)d_out;

    const size_t nX = (size_t)B * T * D;
    u16* Xb = (u16*)d_ws;                          // [B*T, D] bf16
    u16* Wt = Xb + nX;                             // 3 x [D, D] bf16 transposed
    u16* Q  = Wt + 3 * (size_t)D * D;              // [B*T, D]
    u16* Kb = Q + nX;                              // [B*T, D]
    u16* Vt = Kb + nX;                             // [B][D][T] (written by QKV epilogue)
    char* rest = (char*)(Vt + nX);
    const size_t fixed  = (size_t)((char*)rest - (char*)d_ws);
    const size_t perb_E = (size_t)T * T * 2;
    const size_t perb_rs = (size_t)T * 4;
    const bool full = ws_size >= fixed + (size_t)B * (perb_E + perb_rs);
    const int nb = full ? B : 1;
    u16*   E  = (u16*)rest;
    float* RS = (float*)(E + nb * (size_t)T * T);

    const float kfac = 1.4426950408889634f / 32.0f;  // log2(e)/sqrt(d_out)
    const int nTri64 = 272;                           // sum_{bm=0..31} (bm/2+1)

    // 1. casts (W transpose merged into one dispatch)
    cast_x<<<dim3((unsigned)(nX / (8 * 256))), 256, 0, stream>>>(x, Xb, (long long)nX);
    castT_w3<<<dim3(D / 32, D / 32, 3), 256, 0, stream>>>(Wq, Wk, Wv, Wt, D);

    // 2. Merged QKV projection; V lands pre-transposed in Vt
    gemm_bt<M_QKV, 128, 128><<<dim3(3 * D / 128, (B * T) / 128, 1), 256, 0, stream>>>(
        Xb, 0, Wt, 0, Q, (long long)nX, nullptr, Vt, B * T, 3 * D, D, 0.f);

    if (full) {
        hipMemsetAsync(RS, 0, (size_t)B * T * 4, stream);
        // 3. E = exp2(kfac * Q K^T) bf16 (causal) + rowsum; 64x128 tri tiles
        gemm_bt<M_SCORE, 64, 128><<<dim3(nTri64, 1, B), 256, 0, stream>>>(
            Q, (long long)T * D, Kb, (long long)T * D, E, (long long)T * T, RS, nullptr,
            T, T, D, kfac);
        // 4. O = (E Vt^T) / rowsum; 64x128 tiles, K-loop to causal extent
        gemm_bt<M_PV, 64, 128><<<dim3(D / 128, T / 64, B), 256, 0, stream>>>(
            E, (long long)T * T, Vt, (long long)D * T, out, (long long)T * D, RS, nullptr,
            T, D, T, 0.f);
    } else {
        for (int b = 0; b < B; ++b) {
            const size_t ob = (size_t)b * T * D;
            hipMemsetAsync(RS, 0, (size_t)T * 4, stream);
            gemm_bt<M_SCORE, 64, 128><<<dim3(nTri64, 1, 1), 256, 0, stream>>>(
                Q + ob, 0, Kb + ob, 0, E, 0, RS, nullptr, T, T, D, kfac);
            gemm_bt<M_PV, 64, 128><<<dim3(D / 128, T / 64, 1), 256, 0, stream>>>(
                E, 0, Vt + (size_t)b * D * T, 0, out + ob, 0, RS, nullptr, T, D, T, 0.f);
        }
    }
}

// Round 5
// 248.542 us; speedup vs baseline: 1.3291x; 1.0749x over previous
//
#include <hip/hip_runtime.h>
#include <stdint.h>
#include <math.h>

typedef unsigned short u16;
typedef __bf16 bf16x8 __attribute__((ext_vector_type(8)));
typedef float f32x4 __attribute__((ext_vector_type(4)));

#define BK 64   // K-depth per staging iteration (two 32-deep MFMA halves)

enum { M_QKV = 0, M_SCORE = 1, M_PV = 2 };

// fp32 -> bf16 round-to-nearest-even, bit-level
__device__ __forceinline__ u16 f2bf(float f) {
    union { float f; unsigned int u; } a; a.f = f;
    unsigned int u = a.u;
    u += 0x7FFFu + ((u >> 16) & 1u);
    return (u16)(u >> 16);
}

__device__ __forceinline__ void async_load16(const void* g, void* l) {
    __builtin_amdgcn_global_load_lds(
        (const __attribute__((address_space(1))) void*)g,
        (__attribute__((address_space(3))) void*)l,
        16, 0, 0);
}

// ---------------------------------------------------------------------------
// C[M,N] = A[M,K] * Bt[N,K]^T (bf16 in, fp32 acc). 128x128 tile, BK=64,
// 4 waves 2x2, each wave 64x64 (4x4 16x16x32 frags x 2 k-halves = 32 MFMA/iter).
// LDS tile [128][64]: row = 8 granules of 16B; granule (row, q) stored at slot
// q ^ (row & 7). Staging permutes the *global* source granule per lane (the
// LDS destination of global_load_lds must stay wave-uniform-base + lane*16).
// Fragment ds_read_b128 banks spread across all 32 banks (8 lanes/slot = the
// b128 minimum phasing; R3 verified this scheme counts 0 conflicts).
//
// M_QKV : bn 0-7 -> Q, 8-15 -> K, 16-23 -> V, all row-major [B*T, 1024].
// M_SCORE: grid.x = linear lower-tri 128x128 block index; epilogue writes
//          E = exp2(acc*kfac) bf16 (causal-masked) + atomic per-row sum-of-exp.
// M_PV  : K-loop limited to causal extent (bm+1)*128; scales by 1/rowsum.
// ---------------------------------------------------------------------------
template<int MODE>
__global__ __launch_bounds__(256)
void gemm_bt(const u16* __restrict__ A, long long sAb,
             const u16* __restrict__ Bt, long long sBb,
             void* __restrict__ Cv, long long sCb,
             float* __restrict__ rowsum,
             int M, int N, int K, float kfac)
{
    int bm, bn;
    if (MODE == M_SCORE) {
        const int idx = blockIdx.x;
        bm = (int)((sqrtf(8.f * idx + 1.f) - 1.f) * 0.5f);
        while ((bm + 1) * (bm + 2) / 2 <= idx) ++bm;
        while (bm * (bm + 1) / 2 > idx) --bm;
        bn = idx - bm * (bm + 1) / 2;
    } else {
        bn = blockIdx.x; bm = blockIdx.y;
    }
    const int bz = blockIdx.z;
    A  += (size_t)bz * sAb;
    Bt += (size_t)bz * sBb;

    const int tid  = threadIdx.x;
    const int lane = tid & 63;
    const int wv   = tid >> 6;
    const int wm   = wv >> 1;         // wave row (0..1)
    const int wn   = wv & 1;          // wave col (0..1)

    __shared__ __attribute__((aligned(16))) u16 As[128 * BK];
    __shared__ __attribute__((aligned(16))) u16 Bs[128 * BK];

    f32x4 acc[4][4] = {};

    const int rowA0 = bm * 128, rowB0 = bn * 128;
    // Staging: chunk cc = 8 rows x 8 granules (1 KB). lane s -> LDS elem
    // cc*512 + s*8 = (row cc*8 + s/8, slot s&7); that slot holds global
    // granule (s&7) ^ (s>>3)   [row&7 == s>>3].
    const int srow = lane >> 3;
    const int scol = ((lane & 7) ^ (lane >> 3)) * 8;

    int kEnd = K;
    if (MODE == M_PV) { int ke = (bm + 1) * 128; kEnd = ke < K ? ke : K; }

    const int lm   = lane & 15;
    const int quad = lane >> 4;
    const int rx   = lm & 7;          // fragment-row xor (frag row bases % 8 == 0)

    for (int k0 = 0; k0 < kEnd; k0 += BK) {
        #pragma unroll
        for (int c = 0; c < 4; ++c) {
            const int cc = wv * 4 + c;
            const int r  = cc * 8 + srow;
            async_load16(&A[(size_t)(rowA0 + r) * K + k0 + scol], &As[cc * 512 + lane * 8]);
        }
        #pragma unroll
        for (int c = 0; c < 4; ++c) {
            const int cc = wv * 4 + c;
            const int r  = cc * 8 + srow;
            async_load16(&Bt[(size_t)(rowB0 + r) * K + k0 + scol], &Bs[cc * 512 + lane * 8]);
        }
        __syncthreads();

        #pragma unroll
        for (int h = 0; h < 2; ++h) {
            const int slotb = h * 4 + quad;          // logical 16B slot in row
            bf16x8 af[4], bfr[4];
            #pragma unroll
            for (int i = 0; i < 4; ++i)
                af[i] = *reinterpret_cast<const bf16x8*>(
                    &As[(wm * 64 + i * 16 + lm) * BK + (slotb ^ rx) * 8]);
            #pragma unroll
            for (int j = 0; j < 4; ++j)
                bfr[j] = *reinterpret_cast<const bf16x8*>(
                    &Bs[(wn * 64 + j * 16 + lm) * BK + (slotb ^ rx) * 8]);
            #pragma unroll
            for (int i = 0; i < 4; ++i)
                #pragma unroll
                for (int j = 0; j < 4; ++j)
                    acc[i][j] = __builtin_amdgcn_mfma_f32_16x16x32_bf16(af[i], bfr[j], acc[i][j], 0, 0, 0);
        }
        __syncthreads();
    }

    // Epilogue. C/D layout (m89-verified): col = lane&15, row = quad*4 + reg.
    if (MODE == M_QKV) {
        u16* C = (u16*)Cv + (size_t)(bn >> 3) * sCb;  // 0-7:Q, 8-15:K, 16-23:V
        #pragma unroll
        for (int i = 0; i < 4; ++i)
            #pragma unroll
            for (int j = 0; j < 4; ++j) {
                const int r0 = rowA0 + wm * 64 + i * 16 + quad * 4;
                const int c0 = (rowB0 + wn * 64 + j * 16 + lm) & 1023;
                #pragma unroll
                for (int g = 0; g < 4; ++g)
                    C[(size_t)(r0 + g) * 1024 + c0] = f2bf(acc[i][j][g]);
            }
    } else if (MODE == M_SCORE) {
        u16* E = (u16*)Cv + (size_t)bz * sCb;
        float rs[4][4];
        #pragma unroll
        for (int i = 0; i < 4; ++i)
            #pragma unroll
            for (int g = 0; g < 4; ++g) rs[i][g] = 0.f;
        #pragma unroll
        for (int i = 0; i < 4; ++i)
            #pragma unroll
            for (int j = 0; j < 4; ++j) {
                const int r0 = rowA0 + wm * 64 + i * 16 + quad * 4;
                const int c  = rowB0 + wn * 64 + j * 16 + lm;
                #pragma unroll
                for (int g = 0; g < 4; ++g) {
                    const int r = r0 + g;
                    float e = (c <= r) ? exp2f(acc[i][j][g] * kfac) : 0.f;
                    E[(size_t)r * N + c] = f2bf(e);
                    rs[i][g] += e;
                }
            }
        #pragma unroll
        for (int i = 0; i < 4; ++i)
            #pragma unroll
            for (int g = 0; g < 4; ++g) {
                float v = rs[i][g];
                v += __shfl_xor(v, 1); v += __shfl_xor(v, 2);
                v += __shfl_xor(v, 4); v += __shfl_xor(v, 8);
                rs[i][g] = v;
            }
        if (lm == 0) {
            #pragma unroll
            for (int i = 0; i < 4; ++i)
                #pragma unroll
                for (int g = 0; g < 4; ++g) {
                    const int r = rowA0 + wm * 64 + i * 16 + quad * 4 + g;
                    atomicAdd(&rowsum[(size_t)bz * M + r], rs[i][g]);
                }
        }
    } else {  // M_PV
        float* C = (float*)Cv + (size_t)bz * sCb;
        #pragma unroll
        for (int i = 0; i < 4; ++i) {
            const int r0 = rowA0 + wm * 64 + i * 16 + quad * 4;
            float inv[4];
            #pragma unroll
            for (int g = 0; g < 4; ++g)
                inv[g] = 1.f / rowsum[(size_t)bz * M + r0 + g];
            #pragma unroll
            for (int j = 0; j < 4; ++j) {
                const int c0 = rowB0 + wn * 64 + j * 16 + lm;
                #pragma unroll
                for (int g = 0; g < 4; ++g)
                    C[(size_t)(r0 + g) * N + c0] = acc[i][j][g] * inv[g];
            }
        }
    }
}

// x fp32 -> bf16, 8 elems/thread
__global__ __launch_bounds__(256)
void cast_x(const float* __restrict__ x, u16* __restrict__ o, long long n)
{
    long long i = ((long long)blockIdx.x * blockDim.x + threadIdx.x) * 8;
    if (i >= n) return;
    const float4 a = *(const float4*)(x + i);
    const float4 b = *(const float4*)(x + i + 4);
    union { u16 u[8]; float4 v; } r;
    r.u[0] = f2bf(a.x); r.u[1] = f2bf(a.y); r.u[2] = f2bf(a.z); r.u[3] = f2bf(a.w);
    r.u[4] = f2bf(b.x); r.u[5] = f2bf(b.y); r.u[6] = f2bf(b.z); r.u[7] = f2bf(b.w);
    *(float4*)(o + i) = r.v;
}

// W[z][D][D] fp32 -> Wt[z][D][D] bf16 transposed; z selects Wq/Wk/Wv
__global__ __launch_bounds__(256)
void castT_w3(const float* __restrict__ W0, const float* __restrict__ W1,
              const float* __restrict__ W2, u16* __restrict__ Wt, int D)
{
    const float* W = blockIdx.z == 0 ? W0 : (blockIdx.z == 1 ? W1 : W2);
    u16* dst = Wt + (size_t)blockIdx.z * D * D;
    __shared__ u16 t[32][33];
    const int c0 = blockIdx.x * 32, r0 = blockIdx.y * 32;
    const int tx = threadIdx.x & 31, ty = threadIdx.x >> 5;  // ty 0..7
    #pragma unroll
    for (int s = 0; s < 32; s += 8)
        t[ty + s][tx] = f2bf(W[(size_t)(r0 + ty + s) * D + c0 + tx]);
    __syncthreads();
    #pragma unroll
    for (int s = 0; s < 32; s += 8)
        dst[(size_t)(c0 + ty + s) * D + r0 + tx] = t[tx][ty + s];
}

// V[rows][cols] bf16 -> Vt[cols][rows] bf16, batched via blockIdx.z
__global__ __launch_bounds__(256)
void transpose_b(const u16* __restrict__ V, long long sVb,
                 u16* __restrict__ Vt, long long sVtb, int rows, int cols)
{
    V  += (size_t)blockIdx.z * sVb;
    Vt += (size_t)blockIdx.z * sVtb;
    __shared__ u16 t[32][33];
    const int c0 = blockIdx.x * 32, r0 = blockIdx.y * 32;
    const int tx = threadIdx.x & 31, ty = threadIdx.x >> 5;
    #pragma unroll
    for (int s = 0; s < 32; s += 8)
        t[ty + s][tx] = V[(size_t)(r0 + ty + s) * cols + c0 + tx];
    __syncthreads();
    #pragma unroll
    for (int s = 0; s < 32; s += 8)
        Vt[(size_t)(c0 + ty + s) * rows + r0 + tx] = t[tx][ty + s];
}

extern "C" void kernel_launch(void* const* d_in, const int* in_sizes, int n_in,
                              void* d_out, int out_size, void* d_ws, size_t ws_size,
                              hipStream_t stream)
{
    const int B = 4, T = 2048, D = 1024;
    const float* x  = (const float*)d_in[0];
    const float* Wq = (const float*)d_in[1];
    const float* Wk = (const float*)d_in[2];
    const float* Wv = (const float*)d_in[3];
    float* out = (float*)d_out;

    const size_t nX = (size_t)B * T * D;
    u16* Xb = (u16*)d_ws;                          // [B*T, D] bf16
    u16* Wt = Xb + nX;                             // 3 x [D, D] bf16 transposed
    u16* Q  = Wt + 3 * (size_t)D * D;              // [B*T, D]  (Q,K,V contiguous)
    u16* Kb = Q + nX;
    u16* Vb = Kb + nX;
    u16* Vt = Vb + nX;                             // [B][D][T]
    char* rest = (char*)(Vt + nX);
    const size_t fixed   = (size_t)((char*)rest - (char*)d_ws);
    const size_t perb_E  = (size_t)T * T * 2;
    const size_t perb_rs = (size_t)T * 4;
    const bool full = ws_size >= fixed + (size_t)B * (perb_E + perb_rs);
    const int nb = full ? B : 1;
    u16*   E  = (u16*)rest;
    float* RS = (float*)(E + nb * (size_t)T * T);

    const float kfac = 1.4426950408889634f / 32.0f;  // log2(e)/sqrt(d_out)
    const int nTri = (T / 128) * (T / 128 + 1) / 2;  // 136 causal 128x128 blocks

    // 1. casts
    cast_x<<<dim3((unsigned)(nX / (8 * 256))), 256, 0, stream>>>(x, Xb, (long long)nX);
    castT_w3<<<dim3(D / 32, D / 32, 3), 256, 0, stream>>>(Wq, Wk, Wv, Wt, D);

    // 2. Merged QKV projection (BK=64 K-loop, 16 iters)
    gemm_bt<M_QKV><<<dim3(3 * D / 128, (B * T) / 128, 1), 256, 0, stream>>>(
        Xb, 0, Wt, 0, Q, (long long)nX, nullptr, B * T, 3 * D, D, 0.f);

    if (full) {
        hipMemsetAsync(RS, 0, (size_t)B * T * 4, stream);
        // 3. E = exp2(kfac * Q K^T) bf16 (causal) + rowsum; 136 tri blocks/batch
        gemm_bt<M_SCORE><<<dim3(nTri, 1, B), 256, 0, stream>>>(
            Q, (long long)T * D, Kb, (long long)T * D, E, (long long)T * T, RS,
            T, T, D, kfac);
        // 4. V^T
        transpose_b<<<dim3(D / 32, T / 32, B), 256, 0, stream>>>(
            Vb, (long long)T * D, Vt, (long long)D * T, T, D);
        // 5. O = (E Vt^T) / rowsum; K-loop to causal extent
        gemm_bt<M_PV><<<dim3(D / 128, T / 128, B), 256, 0, stream>>>(
            E, (long long)T * T, Vt, (long long)D * T, out, (long long)T * D, RS,
            T, D, T, 0.f);
    } else {
        for (int b = 0; b < B; ++b) {
            const size_t ob = (size_t)b * T * D;
            hipMemsetAsync(RS, 0, (size_t)T * 4, stream);
            gemm_bt<M_SCORE><<<dim3(nTri, 1, 1), 256, 0, stream>>>(
                Q + ob, 0, Kb + ob, 0, E, 0, RS, T, T, D, kfac);
            transpose_b<<<dim3(D / 32, T / 32, 1), 256, 0, stream>>>(
                Vb + ob, 0, Vt, 0, T, D);
            gemm_bt<M_PV><<<dim3(D / 128, T / 128, 1), 256, 0, stream>>>(
                E, 0, Vt, 0, out + ob, 0, RS, T, D, T, 0.f);
        }
    }
}